// Round 15
// baseline (633.798 us; speedup 1.0000x reference)
//
#include <hip/hip_runtime.h>
#include <hip/hip_bf16.h>
#include <math.h>

typedef unsigned int uint;
typedef unsigned short ushort;
using f32x4 = __attribute__((ext_vector_type(4))) float;
using s16x8 = __attribute__((ext_vector_type(8))) short;

#define NSLOT 32   // replicated BN-stat buffers (de-contend epilogue atomics; 1024 gather blocks)

__device__ __forceinline__ float bflo(uint u) { return __uint_as_float(u << 16); }
__device__ __forceinline__ float bfhi(uint u) { return __uint_as_float(u & 0xffff0000u); }
__device__ __forceinline__ ushort f2bf(float f) {
    uint u = __float_as_uint(f);
    return (ushort)((u + 0x7fffu + ((u >> 16) & 1u)) >> 16);   // RNE
}
__device__ __forceinline__ float sel4f(float a, float b, float c, float d, int i) {
    float r = a; r = (i == 1) ? b : r; r = (i == 2) ? c : r; r = (i == 3) ? d : r; return r;
}
__device__ __forceinline__ int sel4i(int a, int b, int c, int d, int i) {
    int r = a; r = (i == 1) ? b : r; r = (i == 2) ? c : r; r = (i == 3) ? d : r; return r;
}

// ---------------- Fat init: zero (degc|bnpartA|bnpartB|ctrs) blocks + weight-prep blocks ----------

__global__ __launch_bounds__(256) void init_prep(uint4* __restrict__ zbase, int nz, int ZB,
                                                 const float* __restrict__ W1,
                                                 const float* __restrict__ W2,
                                                 const float* __restrict__ W3,
                                                 const float* __restrict__ l2w,
                                                 const float* __restrict__ l2b,
                                                 ushort* __restrict__ wt1,
                                                 ushort* __restrict__ wt2,
                                                 ushort* __restrict__ wt3,
                                                 ushort* __restrict__ w2bf,
                                                 float* __restrict__ b2pad) {
    int bid = blockIdx.x;
    if (bid < ZB) {
        int i = bid * 256 + threadIdx.x;
        if (i < nz) zbase[i] = (uint4){0u, 0u, 0u, 0u};
        return;
    }
    int i = (bid - ZB) * 256 + threadIdx.x;      // 0..49151
    int li = i & 16383;
    int k = li >> 7, n = li & 127;
    const float* Ws = (i < 16384) ? W1 : (i < 32768) ? W2 : W3;
    ushort* Wd = (i < 16384) ? wt1 : (i < 32768) ? wt2 : wt3;
    Wd[n * 128 + k] = f2bf(Ws[li]);
    if (i < 2048) {                               // W2bf [16 classes][128 k], rows 10..15 = 0
        int c = i >> 7, kk = i & 127;
        float v = (c < 10) ? l2w[kk * 10 + c] : 0.f;
        w2bf[c * 128 + kk] = f2bf(v);
    }
    if (i < 16) b2pad[i] = (i < 10) ? l2b[i] : -1e30f;
}

// ---------------- Degree count (4 edges/thread) ----------------

__global__ __launch_bounds__(256) void deg_count(const int* __restrict__ dst,
                                                 int* __restrict__ deg, int E) {
    int base = blockIdx.x * 1024 + threadIdx.x;
    int d[4]; bool ok[4];
    #pragma unroll
    for (int k = 0; k < 4; ++k) {
        int e = base + k * 256;
        ok[k] = e < E;
        d[k] = ok[k] ? dst[e] : 0;
    }
    #pragma unroll
    for (int k = 0; k < 4; ++k)
        if (ok[k]) atomicAdd(&deg[d[k]], 1);
}

// ---------------- Merged scan: per-block sum -> publish/spin -> rowstart/cursor/dinv ----------------

__global__ __launch_bounds__(256) void scan_fill(const int* __restrict__ deg,
                                                 int* __restrict__ bsum,
                                                 int* __restrict__ sync_ctr,
                                                 int* __restrict__ row_start,
                                                 int* __restrict__ cursor,
                                                 float* __restrict__ dinv,
                                                 int N, int E, int nblk) {
    __shared__ int s[256];
    __shared__ int sb[256];
    int t = threadIdx.x;
    int bid = blockIdx.x;
    int i = bid * 256 + t;
    int dg = (i < N) ? deg[i] : 0;
    s[t] = dg;
    __syncthreads();
    for (int off = 1; off < 256; off <<= 1) {
        int v = (t >= off) ? s[t - off] : 0;
        __syncthreads();
        s[t] += v;
        __syncthreads();
    }
    if (t == 0) {
        bsum[bid] = s[255];
        __threadfence();
        atomicAdd(sync_ctr, 1);
        while (atomicAdd(sync_ctr, 0) < nblk) __builtin_amdgcn_s_sleep(8);
    }
    __syncthreads();
    sb[t] = (t < nblk) ? atomicAdd(&bsum[t], 0) : 0;
    __syncthreads();
    for (int off = 1; off < 256; off <<= 1) {
        int v = (t >= off) ? sb[t - off] : 0;
        __syncthreads();
        sb[t] += v;
        __syncthreads();
    }
    if (i < N) {
        int boff = (bid == 0) ? 0 : sb[bid - 1];
        int excl = boff + s[t] - dg;
        row_start[i] = excl;
        cursor[i] = excl;
        dinv[i] = rsqrtf((float)dg + 1.0f);
    }
    if (i == 0) row_start[N] = E;
}

// ---------------- src-only CSR fill (4 edges/thread) ----------------

__global__ __launch_bounds__(256) void csr_fill(const int* __restrict__ src,
                                                const int* __restrict__ dst,
                                                int* __restrict__ cursor,
                                                int* __restrict__ csr_src, int E) {
    int base = blockIdx.x * 1024 + threadIdx.x;
    int s[4], d[4]; bool ok[4];
    #pragma unroll
    for (int k = 0; k < 4; ++k) {
        int e = base + k * 256;
        ok[k] = e < E;
        s[k] = ok[k] ? src[e] : 0;
        d[k] = ok[k] ? dst[e] : 0;
    }
    #pragma unroll
    for (int k = 0; k < 4; ++k) {
        if (ok[k]) {
            int p = atomicAdd(&cursor[d[k]], 1);
            csr_src[p] = s[k];
        }
    }
}

// ---------------- bf16 MFMA GEMM: 128 rows/block, B staged once ----------------
// AFF: BN scale/shift computed IN-BLOCK from bnpart slots (replaces bnfinalize dispatch).
// PRESCALE: epilogue multiplies row by dinv[row]. HEAD: fused logits + log_softmax.

template<bool XF32, bool AFF, bool PRESCALE, bool HEAD>
__global__ __launch_bounds__(256) void gemm_mfma(const void* __restrict__ Xv,
                                                 const float* __restrict__ bnp,
                                                 const float* __restrict__ gamma,
                                                 const float* __restrict__ beta,
                                                 float invN,
                                                 const ushort* __restrict__ Bt,
                                                 const float* __restrict__ bias,
                                                 const float* __restrict__ dinv,
                                                 ushort* __restrict__ Y,
                                                 const ushort* __restrict__ W2bf,
                                                 const float* __restrict__ b2pad,
                                                 float* __restrict__ OUT, int N) {
    __shared__ char smem[2 * 16384 + 32768];
    __shared__ float sscale[128], sshift[128];
    char* Bl = smem + 32768;    // 128 n-rows x 256B, swizzled: unit u at n*256 + (u^(n&7))*16

    int tid = threadIdx.x;
    int brow = blockIdx.x * 128;

    // BN prologue: reduce NSLOT stat slots -> scale/shift in LDS (coherent via kernel boundary)
    if (AFF) {
        if (tid < 128) {
            float sum = 0.f, ss = 0.f;
            #pragma unroll 8
            for (int s = 0; s < NSLOT; ++s) {
                sum += bnp[s * 256 + tid];
                ss  += bnp[s * 256 + 128 + tid];
            }
            float mu  = sum * invN;
            float var = ss * invN - mu * mu;
            float sc  = gamma[tid] * rsqrtf(var + 1e-5f);
            sscale[tid] = sc;
            sshift[tid] = beta[tid] - mu * sc;
        }
    }

    // stage B (once)
    {
        int n = tid >> 1, h = tid & 1;
        const uint4* srcp = (const uint4*)(Bt + n * 128 + h * 64);
        #pragma unroll
        for (int i = 0; i < 8; ++i) {
            uint4 v = srcp[i];
            int u = (h * 8 + i) ^ (n & 7);
            *(uint4*)(Bl + n * 256 + u * 16) = v;
        }
    }
    __syncthreads();   // sscale/sshift visible to all before A staging

    int lane = tid & 63, w = tid >> 6;
    int m = lane & 15, g = lane >> 4;
    int wr = w * 16;

    #pragma unroll
    for (int t = 0; t < 2; ++t) {
        char* Al = smem + t * 16384;    // 64 rows x 256B, swizzled
        int rbase = brow + t * 64;

        // stage A tile t
        {
            int r = tid >> 2, c0 = (tid & 3) * 32;
            int row = rbase + r;
            bool ok = row < N;
            uint pk[16];
            if (XF32) {
                const float* Xr = (const float*)Xv + (size_t)row * 128 + c0;
                #pragma unroll
                for (int i = 0; i < 16; ++i) {
                    float f0 = ok ? Xr[i * 2] : 0.f;
                    float f1 = ok ? Xr[i * 2 + 1] : 0.f;
                    pk[i] = (uint)f2bf(f0) | ((uint)f2bf(f1) << 16);
                }
            } else {
                const uint* Xr = (const uint*)((const ushort*)Xv + (size_t)row * 128 + c0);
                #pragma unroll
                for (int i = 0; i < 16; ++i) {
                    uint u = ok ? Xr[i] : 0u;
                    float f0 = bflo(u), f1 = bfhi(u);
                    if (AFF) {
                        int c = c0 + i * 2;
                        f0 = f0 * sscale[c] + sshift[c];
                        f1 = f1 * sscale[c + 1] + sshift[c + 1];
                    }
                    pk[i] = (uint)f2bf(f0) | ((uint)f2bf(f1) << 16);
                }
            }
            #pragma unroll
            for (int i = 0; i < 4; ++i) {
                int u = ((tid & 3) * 4 + i) ^ (r & 7);
                *(uint4*)(Al + r * 256 + u * 16) = *(uint4*)&pk[i * 4];
            }
        }
        __syncthreads();

        f32x4 acc[8];
        #pragma unroll
        for (int nt = 0; nt < 8; ++nt) acc[nt] = (f32x4){0.f, 0.f, 0.f, 0.f};

        #pragma unroll
        for (int kk = 0; kk < 4; ++kk) {
            int u = (kk * 4 + g) ^ (m & 7);
            s16x8 a = *(const s16x8*)(Al + (wr + m) * 256 + u * 16);
            #pragma unroll
            for (int nt = 0; nt < 8; ++nt) {
                s16x8 b = *(const s16x8*)(Bl + (nt * 16 + m) * 256 + u * 16);
                acc[nt] = __builtin_amdgcn_mfma_f32_16x16x32_bf16(a, b, acc[nt], 0, 0, 0);
            }
        }

        if (!HEAD) {
            #pragma unroll
            for (int i = 0; i < 4; ++i) {
                int row = rbase + wr + g * 4 + i;
                if (row < N) {
                    float dv = PRESCALE ? dinv[row] : 1.f;
                    #pragma unroll
                    for (int nt = 0; nt < 8; ++nt) {
                        float v = acc[nt][i];
                        if (PRESCALE) v *= dv;
                        Y[(size_t)row * 128 + nt * 16 + m] = f2bf(v);
                    }
                }
            }
        } else {
            float bv[8];
            #pragma unroll
            for (int nt = 0; nt < 8; ++nt) bv[nt] = bias[nt * 16 + m];
            // write this wave's 16 h rows (bias+relu, bf16) into its OWN A-LDS rows (frag layout)
            #pragma unroll
            for (int i = 0; i < 4; ++i) {
                int r = wr + g * 4 + i;
                #pragma unroll
                for (int nt = 0; nt < 8; ++nt) {
                    float v = fmaxf(acc[nt][i] + bv[nt], 0.f);
                    int col = nt * 16 + m;
                    int u = (col >> 3) ^ (r & 7);
                    *(ushort*)(Al + r * 256 + u * 16 + (col & 7) * 2) = f2bf(v);
                }
            }
            __syncthreads();
            float b2v = b2pad[m];
            f32x4 lg = (f32x4){b2v, b2v, b2v, b2v};
            #pragma unroll
            for (int kk = 0; kk < 4; ++kk) {
                int u = (kk * 4 + g) ^ (m & 7);
                s16x8 a = *(const s16x8*)(Al + (wr + m) * 256 + u * 16);
                s16x8 b = *(const s16x8*)(&W2bf[m * 128 + (kk * 4 + g) * 8]);
                lg = __builtin_amdgcn_mfma_f32_16x16x32_bf16(a, b, lg, 0, 0, 0);
            }
            #pragma unroll
            for (int i = 0; i < 4; ++i) {
                float v = lg[i];
                float mx = v;
                #pragma unroll
                for (int off = 8; off > 0; off >>= 1) mx = fmaxf(mx, __shfl_xor(mx, off, 64));
                float ex = expf(v - mx);
                float sm = ex;
                #pragma unroll
                for (int off = 8; off > 0; off >>= 1) sm += __shfl_xor(sm, off, 64);
                float res = v - (mx + logf(sm));
                int grow = rbase + wr + g * 4 + i;
                if (m < 10 && grow < N) OUT[(size_t)grow * 10 + m] = res;
            }
        }
    }
}

// ---------------- Persistent gather (work-stealing waves) + self-loop + bias + ReLU + BN stats ----
// NO device fences (R10: per-block __threadfence destroyed H's L2 residency, 7x regression).
// Relaxed atomic work-steal is safe (no cache-flush semantics).

__global__ __launch_bounds__(256) void gather_fused(const ushort* __restrict__ H,
                                                    const int* __restrict__ row_start,
                                                    const int* __restrict__ csr_src,
                                                    const float* __restrict__ dinv,
                                                    const float* __restrict__ bias,
                                                    ushort* __restrict__ Y,
                                                    float* __restrict__ bnpart,
                                                    int* __restrict__ wctr, int N) {
    int g = threadIdx.x >> 6, lane = threadIdx.x & 63;
    int d = lane * 2;
    float b0 = bias[d], b1 = bias[d + 1];
    float s0 = 0.f, s1 = 0.f, ss0 = 0.f, ss1 = 0.f;

    int nchunks = (N + 3) / 4;

    for (;;) {
        int chunk = 0;
        if (lane == 0) chunk = atomicAdd(wctr, 1);
        chunk = __shfl(chunk, 0);
        if (chunk >= nchunks) break;

        int c = chunk * 4;
        int nn = min(4, N - c);

        int rsv = row_start[c + min(lane, nn)];
        int rs0 = __shfl(rsv, 0);
        int rs1 = __shfl(rsv, min(1, nn));
        int rs2 = __shfl(rsv, min(2, nn));
        int rs3 = __shfl(rsv, min(3, nn));
        int rs4 = __shfl(rsv, nn);

        float dvv = dinv[c + min(lane, nn - 1)];
        float dv0 = __shfl(dvv, 0);
        float dv1 = __shfl(dvv, min(1, nn - 1));
        float dv2 = __shfl(dvv, min(2, nn - 1));
        float dv3 = __shfl(dvv, min(3, nn - 1));

        uint h0 = *(const uint*)&H[(size_t)c * 128 + d];
        uint h1 = (nn > 1) ? *(const uint*)&H[(size_t)(c + 1) * 128 + d] : 0u;
        uint h2 = (nn > 2) ? *(const uint*)&H[(size_t)(c + 2) * 128 + d] : 0u;
        uint h3 = (nn > 3) ? *(const uint*)&H[(size_t)(c + 3) * 128 + d] : 0u;

        float i0_0 = bflo(h0) * dv0 + b0, i1_0 = bfhi(h0) * dv0 + b1;
        float i0_1 = bflo(h1) * dv1 + b0, i1_1 = bfhi(h1) * dv1 + b1;
        float i0_2 = bflo(h2) * dv2 + b0, i1_2 = bfhi(h2) * dv2 + b1;
        float i0_3 = bflo(h3) * dv3 + b0, i1_3 = bfhi(h3) * dv3 + b1;

        int e0 = rs0, eend = rs4;
        int seg = 0;
        int nextb = rs1;
        float i0s = i0_0, i1s = i1_0, dvs = dv0;
        float es0 = 0.f, es1 = 0.f;

        for (int base = e0; base < eend; base += 64) {
            int cnt = min(64, eend - base);
            int sl = (lane < cnt) ? csr_src[base + lane] : 0;

            for (int j = 0; j < cnt; j += 16) {
                int mm = min(16, cnt - j);
                uint v[16];
                #pragma unroll
                for (int k = 0; k < 16; ++k) {
                    int idx = min(j + k, cnt - 1);
                    int sk = __shfl(sl, idx);
                    v[k] = *(const uint*)&H[(size_t)sk * 128 + d];
                }
                #pragma unroll
                for (int k = 0; k < 16; ++k) {
                    if (k < mm) {
                        int e = base + j + k;
                        while (e >= nextb) {     // uniform boundary crossing
                            float r0 = fmaxf(es0 * dvs + i0s, 0.f);
                            float r1 = fmaxf(es1 * dvs + i1s, 0.f);
                            *(uint*)&Y[(size_t)(c + seg) * 128 + d] =
                                (uint)f2bf(r0) | ((uint)f2bf(r1) << 16);
                            s0 += r0; ss0 += r0 * r0; s1 += r1; ss1 += r1 * r1;
                            seg++;
                            i0s = sel4f(i0_0, i0_1, i0_2, i0_3, seg);
                            i1s = sel4f(i1_0, i1_1, i1_2, i1_3, seg);
                            dvs = sel4f(dv0, dv1, dv2, dv3, seg);
                            nextb = sel4i(rs1, rs2, rs3, rs4, seg);
                            es0 = 0.f; es1 = 0.f;
                        }
                        es0 += bflo(v[k]);
                        es1 += bfhi(v[k]);
                    }
                }
            }
        }
        for (;;) {
            float r0 = fmaxf(es0 * dvs + i0s, 0.f);
            float r1 = fmaxf(es1 * dvs + i1s, 0.f);
            *(uint*)&Y[(size_t)(c + seg) * 128 + d] = (uint)f2bf(r0) | ((uint)f2bf(r1) << 16);
            s0 += r0; ss0 += r0 * r0; s1 += r1; ss1 += r1 * r1;
            seg++;
            if (seg >= nn) break;
            i0s = sel4f(i0_0, i0_1, i0_2, i0_3, seg);
            i1s = sel4f(i1_0, i1_1, i1_2, i1_3, seg);
            dvs = sel4f(dv0, dv1, dv2, dv3, seg);
            nextb = sel4i(rs1, rs2, rs3, rs4, seg);
            es0 = 0.f; es1 = 0.f;
        }
    }

    float* bp = bnpart + (size_t)(blockIdx.x & (NSLOT - 1)) * 256;   // [0..127]=sum [128..255]=ss
    __shared__ float red[4][128];
    red[g][d] = s0; red[g][d + 1] = s1;
    __syncthreads();
    if (g == 0) {
        atomicAdd(&bp[d],     red[0][d] + red[1][d] + red[2][d] + red[3][d]);
        atomicAdd(&bp[d + 1], red[0][d + 1] + red[1][d + 1] + red[2][d + 1] + red[3][d + 1]);
    }
    __syncthreads();
    red[g][d] = ss0; red[g][d + 1] = ss1;
    __syncthreads();
    if (g == 0) {
        atomicAdd(&bp[128 + d],     red[0][d] + red[1][d] + red[2][d] + red[3][d]);
        atomicAdd(&bp[128 + d + 1], red[0][d + 1] + red[1][d + 1] + red[2][d + 1] + red[3][d + 1]);
    }
}

// ---------------- Launch ----------------

static inline char* align16(char* p) { return (char*)(((uintptr_t)p + 15) & ~(uintptr_t)15); }

extern "C" void kernel_launch(void* const* d_in, const int* in_sizes, int n_in,
                              void* d_out, int out_size, void* d_ws, size_t ws_size,
                              hipStream_t stream) {
    const float* x    = (const float*)d_in[0];
    const int*   ei   = (const int*)d_in[1];
    const float* W1   = (const float*)d_in[2];
    const float* b1   = (const float*)d_in[3];
    const float* g1   = (const float*)d_in[4];
    const float* be1  = (const float*)d_in[5];
    const float* W2   = (const float*)d_in[6];
    const float* b2   = (const float*)d_in[7];
    const float* g2   = (const float*)d_in[8];
    const float* be2  = (const float*)d_in[9];
    const float* l1w  = (const float*)d_in[10];
    const float* l1b  = (const float*)d_in[11];
    const float* l2w  = (const float*)d_in[12];
    const float* l2b  = (const float*)d_in[13];
    float* out = (float*)d_out;

    int N = in_sizes[0] / 128;   // 50000
    int E = in_sizes[1] / 2;     // 640000
    const int* srcp = ei;
    const int* dstp = ei + E;

    char* w = (char*)d_ws;
    ushort* bufA   = (ushort*)w;  w = align16(w + (size_t)N * 128 * 2);
    ushort* bufB   = (ushort*)w;  w = align16(w + (size_t)N * 128 * 2);
    // zero region: degc | bnpartA | bnpartB | ctrs (contiguous, uint4-granular)
    char* zstart   = w;
    int*   degc    = (int*)w;     w += (size_t)N * 4;
    float* bnpA    = (float*)w;   w += (size_t)NSLOT * 256 * 4;
    float* bnpB    = (float*)w;   w += (size_t)NSLOT * 256 * 4;
    int*   ctrs    = (int*)w;     w += 16;   // [0]=scan sync, [1]=gather1 steal, [2]=gather2 steal
    size_t zbytes  = (size_t)(w - zstart);
    w = align16(w);
    float* dinv    = (float*)w;   w = align16(w + (size_t)N * 4);
    int*   row_st  = (int*)w;     w = align16(w + (size_t)(N + 1) * 4);
    int*   cursor  = (int*)w;     w = align16(w + (size_t)N * 4);
    int*   bsum    = (int*)w;     w = align16(w + 256 * 4);
    int*   csr_src = (int*)w;     w = align16(w + (size_t)E * 4);
    ushort* wt1    = (ushort*)w;  w = align16(w + 16384 * 2);
    ushort* wt2    = (ushort*)w;  w = align16(w + 16384 * 2);
    ushort* wt3    = (ushort*)w;  w = align16(w + 16384 * 2);
    ushort* w2bf   = (ushort*)w;  w = align16(w + 2048 * 2);
    float* b2pad   = (float*)w;   w = align16(w + 16 * 4);

    int nz = (int)(zbytes / 16);             // uint4 count (zbytes is 16B-multiple)
    int ZB = (nz + 255) / 256;               // zeroing blocks
    int eg4 = (E + 1023) / 1024;
    int ng = (N + 255) / 256;                // scan block count (196 <= 256 CUs)
    int gemm_grid = (N + 127) / 128;         // 391
    int gather_grid = 1024;                  // persistent, 4 blocks/CU
    float invN = 1.0f / (float)N;

    // ---- init (zero ∥ weight prep), CSR build ----
    init_prep<<<ZB + 192, 256, 0, stream>>>((uint4*)zstart, nz, ZB,
                                            W1, W2, l1w, l2w, l2b, wt1, wt2, wt3, w2bf, b2pad);
    deg_count<<<eg4, 256, 0, stream>>>(dstp, degc, E);
    scan_fill<<<ng, 256, 0, stream>>>(degc, bsum, &ctrs[0], row_st, cursor, dinv, N, E, ng);
    csr_fill<<<eg4, 256, 0, stream>>>(srcp, dstp, cursor, csr_src, E);

    // ---- layer 1 ----
    gemm_mfma<true, false, true, false><<<gemm_grid, 256, 0, stream>>>(
        x, nullptr, nullptr, nullptr, 0.f, wt1, nullptr, dinv, bufA, nullptr, nullptr, nullptr, N);
    gather_fused<<<gather_grid, 256, 0, stream>>>(bufA, row_st, csr_src, dinv, b1, bufB,
                                                  bnpA, &ctrs[1], N);

    // ---- layer 2 (BN1 folded into GEMM prologue from bnpA) ----
    gemm_mfma<false, true, true, false><<<gemm_grid, 256, 0, stream>>>(
        bufB, bnpA, g1, be1, invN, wt2, nullptr, dinv, bufA, nullptr, nullptr, nullptr, N);
    gather_fused<<<gather_grid, 256, 0, stream>>>(bufA, row_st, csr_src, dinv, b2, bufB,
                                                  bnpB, &ctrs[2], N);

    // ---- head: lin1 GEMM (BN2 from bnpB) + MFMA logits + lane-tree log_softmax ----
    gemm_mfma<false, true, false, true><<<gemm_grid, 256, 0, stream>>>(
        bufB, bnpB, g2, be2, invN, wt3, l1b, nullptr, nullptr, w2bf, b2pad, out, N);
}

// Round 16
// 300.679 us; speedup vs baseline: 2.1079x; 2.1079x over previous
//
#include <hip/hip_runtime.h>
#include <hip/hip_bf16.h>
#include <math.h>

typedef unsigned int uint;
typedef unsigned short ushort;
using f32x4 = __attribute__((ext_vector_type(4))) float;
using s16x8 = __attribute__((ext_vector_type(8))) short;

#define NSLOT 64   // replicated BN-stat buffers (matches 3125-block gather fan-in, R11-proven)

__device__ __forceinline__ float bflo(uint u) { return __uint_as_float(u << 16); }
__device__ __forceinline__ float bfhi(uint u) { return __uint_as_float(u & 0xffff0000u); }
__device__ __forceinline__ ushort f2bf(float f) {
    uint u = __float_as_uint(f);
    return (ushort)((u + 0x7fffu + ((u >> 16) & 1u)) >> 16);   // RNE
}
__device__ __forceinline__ float sel4f(float a, float b, float c, float d, int i) {
    float r = a; r = (i == 1) ? b : r; r = (i == 2) ? c : r; r = (i == 3) ? d : r; return r;
}
__device__ __forceinline__ int sel4i(int a, int b, int c, int d, int i) {
    int r = a; r = (i == 1) ? b : r; r = (i == 2) ? c : r; r = (i == 3) ? d : r; return r;
}

// ---------------- Fat init: zero (degc|bnpartA|bnpartB|ctrs) blocks + weight-prep blocks ----------

__global__ __launch_bounds__(256) void init_prep(uint4* __restrict__ zbase, int nz, int ZB,
                                                 const float* __restrict__ W1,
                                                 const float* __restrict__ W2,
                                                 const float* __restrict__ W3,
                                                 const float* __restrict__ l2w,
                                                 const float* __restrict__ l2b,
                                                 ushort* __restrict__ wt1,
                                                 ushort* __restrict__ wt2,
                                                 ushort* __restrict__ wt3,
                                                 ushort* __restrict__ w2bf,
                                                 float* __restrict__ b2pad) {
    int bid = blockIdx.x;
    if (bid < ZB) {
        int i = bid * 256 + threadIdx.x;
        if (i < nz) zbase[i] = (uint4){0u, 0u, 0u, 0u};
        return;
    }
    int i = (bid - ZB) * 256 + threadIdx.x;      // 0..49151
    int li = i & 16383;
    int k = li >> 7, n = li & 127;
    const float* Ws = (i < 16384) ? W1 : (i < 32768) ? W2 : W3;
    ushort* Wd = (i < 16384) ? wt1 : (i < 32768) ? wt2 : wt3;
    Wd[n * 128 + k] = f2bf(Ws[li]);
    if (i < 2048) {                               // W2bf [16 classes][128 k], rows 10..15 = 0
        int c = i >> 7, kk = i & 127;
        float v = (c < 10) ? l2w[kk * 10 + c] : 0.f;
        w2bf[c * 128 + kk] = f2bf(v);
    }
    if (i < 16) b2pad[i] = (i < 10) ? l2b[i] : -1e30f;
}

// ---------------- Degree count (4 edges/thread) ----------------

__global__ __launch_bounds__(256) void deg_count(const int* __restrict__ dst,
                                                 int* __restrict__ deg, int E) {
    int base = blockIdx.x * 1024 + threadIdx.x;
    int d[4]; bool ok[4];
    #pragma unroll
    for (int k = 0; k < 4; ++k) {
        int e = base + k * 256;
        ok[k] = e < E;
        d[k] = ok[k] ? dst[e] : 0;
    }
    #pragma unroll
    for (int k = 0; k < 4; ++k)
        if (ok[k]) atomicAdd(&deg[d[k]], 1);
}

// ---------------- Merged scan: per-block sum -> publish/spin -> rowstart/cursor/dinv ----------------

__global__ __launch_bounds__(256) void scan_fill(const int* __restrict__ deg,
                                                 int* __restrict__ bsum,
                                                 int* __restrict__ sync_ctr,
                                                 int* __restrict__ row_start,
                                                 int* __restrict__ cursor,
                                                 float* __restrict__ dinv,
                                                 int N, int E, int nblk) {
    __shared__ int s[256];
    __shared__ int sb[256];
    int t = threadIdx.x;
    int bid = blockIdx.x;
    int i = bid * 256 + t;
    int dg = (i < N) ? deg[i] : 0;
    s[t] = dg;
    __syncthreads();
    for (int off = 1; off < 256; off <<= 1) {
        int v = (t >= off) ? s[t - off] : 0;
        __syncthreads();
        s[t] += v;
        __syncthreads();
    }
    if (t == 0) {
        bsum[bid] = s[255];
        __threadfence();
        atomicAdd(sync_ctr, 1);
        while (atomicAdd(sync_ctr, 0) < nblk) __builtin_amdgcn_s_sleep(8);
    }
    __syncthreads();
    sb[t] = (t < nblk) ? atomicAdd(&bsum[t], 0) : 0;
    __syncthreads();
    for (int off = 1; off < 256; off <<= 1) {
        int v = (t >= off) ? sb[t - off] : 0;
        __syncthreads();
        sb[t] += v;
        __syncthreads();
    }
    if (i < N) {
        int boff = (bid == 0) ? 0 : sb[bid - 1];
        int excl = boff + s[t] - dg;
        row_start[i] = excl;
        cursor[i] = excl;
        dinv[i] = rsqrtf((float)dg + 1.0f);
    }
    if (i == 0) row_start[N] = E;
}

// ---------------- src-only CSR fill (4 edges/thread) ----------------

__global__ __launch_bounds__(256) void csr_fill(const int* __restrict__ src,
                                                const int* __restrict__ dst,
                                                int* __restrict__ cursor,
                                                int* __restrict__ csr_src, int E) {
    int base = blockIdx.x * 1024 + threadIdx.x;
    int s[4], d[4]; bool ok[4];
    #pragma unroll
    for (int k = 0; k < 4; ++k) {
        int e = base + k * 256;
        ok[k] = e < E;
        s[k] = ok[k] ? src[e] : 0;
        d[k] = ok[k] ? dst[e] : 0;
    }
    #pragma unroll
    for (int k = 0; k < 4; ++k) {
        if (ok[k]) {
            int p = atomicAdd(&cursor[d[k]], 1);
            csr_src[p] = s[k];
        }
    }
}

// ---------------- bf16 MFMA GEMM: 128 rows/block, B staged once ----------------
// AFF: BN scale/shift computed IN-BLOCK from bnpart slots (replaces bnfinalize dispatch).
// PRESCALE: epilogue multiplies row by dinv[row]. HEAD: fused logits + log_softmax.

template<bool XF32, bool AFF, bool PRESCALE, bool HEAD>
__global__ __launch_bounds__(256) void gemm_mfma(const void* __restrict__ Xv,
                                                 const float* __restrict__ bnp,
                                                 const float* __restrict__ gamma,
                                                 const float* __restrict__ beta,
                                                 float invN,
                                                 const ushort* __restrict__ Bt,
                                                 const float* __restrict__ bias,
                                                 const float* __restrict__ dinv,
                                                 ushort* __restrict__ Y,
                                                 const ushort* __restrict__ W2bf,
                                                 const float* __restrict__ b2pad,
                                                 float* __restrict__ OUT, int N) {
    __shared__ char smem[2 * 16384 + 32768];
    __shared__ float sscale[128], sshift[128];
    char* Bl = smem + 32768;    // 128 n-rows x 256B, swizzled: unit u at n*256 + (u^(n&7))*16

    int tid = threadIdx.x;
    int brow = blockIdx.x * 128;

    // BN prologue: reduce NSLOT stat slots -> scale/shift in LDS (coherent via kernel boundary)
    if (AFF) {
        if (tid < 128) {
            float sum = 0.f, ss = 0.f;
            #pragma unroll 8
            for (int s = 0; s < NSLOT; ++s) {
                sum += bnp[s * 256 + tid];
                ss  += bnp[s * 256 + 128 + tid];
            }
            float mu  = sum * invN;
            float var = ss * invN - mu * mu;
            float sc  = gamma[tid] * rsqrtf(var + 1e-5f);
            sscale[tid] = sc;
            sshift[tid] = beta[tid] - mu * sc;
        }
    }

    // stage B (once)
    {
        int n = tid >> 1, h = tid & 1;
        const uint4* srcp = (const uint4*)(Bt + n * 128 + h * 64);
        #pragma unroll
        for (int i = 0; i < 8; ++i) {
            uint4 v = srcp[i];
            int u = (h * 8 + i) ^ (n & 7);
            *(uint4*)(Bl + n * 256 + u * 16) = v;
        }
    }
    __syncthreads();   // sscale/sshift visible to all before A staging

    int lane = tid & 63, w = tid >> 6;
    int m = lane & 15, g = lane >> 4;
    int wr = w * 16;

    #pragma unroll
    for (int t = 0; t < 2; ++t) {
        char* Al = smem + t * 16384;    // 64 rows x 256B, swizzled
        int rbase = brow + t * 64;

        // stage A tile t
        {
            int r = tid >> 2, c0 = (tid & 3) * 32;
            int row = rbase + r;
            bool ok = row < N;
            uint pk[16];
            if (XF32) {
                const float* Xr = (const float*)Xv + (size_t)row * 128 + c0;
                #pragma unroll
                for (int i = 0; i < 16; ++i) {
                    float f0 = ok ? Xr[i * 2] : 0.f;
                    float f1 = ok ? Xr[i * 2 + 1] : 0.f;
                    pk[i] = (uint)f2bf(f0) | ((uint)f2bf(f1) << 16);
                }
            } else {
                const uint* Xr = (const uint*)((const ushort*)Xv + (size_t)row * 128 + c0);
                #pragma unroll
                for (int i = 0; i < 16; ++i) {
                    uint u = ok ? Xr[i] : 0u;
                    float f0 = bflo(u), f1 = bfhi(u);
                    if (AFF) {
                        int c = c0 + i * 2;
                        f0 = f0 * sscale[c] + sshift[c];
                        f1 = f1 * sscale[c + 1] + sshift[c + 1];
                    }
                    pk[i] = (uint)f2bf(f0) | ((uint)f2bf(f1) << 16);
                }
            }
            #pragma unroll
            for (int i = 0; i < 4; ++i) {
                int u = ((tid & 3) * 4 + i) ^ (r & 7);
                *(uint4*)(Al + r * 256 + u * 16) = *(uint4*)&pk[i * 4];
            }
        }
        __syncthreads();

        f32x4 acc[8];
        #pragma unroll
        for (int nt = 0; nt < 8; ++nt) acc[nt] = (f32x4){0.f, 0.f, 0.f, 0.f};

        #pragma unroll
        for (int kk = 0; kk < 4; ++kk) {
            int u = (kk * 4 + g) ^ (m & 7);
            s16x8 a = *(const s16x8*)(Al + (wr + m) * 256 + u * 16);
            #pragma unroll
            for (int nt = 0; nt < 8; ++nt) {
                s16x8 b = *(const s16x8*)(Bl + (nt * 16 + m) * 256 + u * 16);
                acc[nt] = __builtin_amdgcn_mfma_f32_16x16x32_bf16(a, b, acc[nt], 0, 0, 0);
            }
        }

        if (!HEAD) {
            #pragma unroll
            for (int i = 0; i < 4; ++i) {
                int row = rbase + wr + g * 4 + i;
                if (row < N) {
                    float dv = PRESCALE ? dinv[row] : 1.f;
                    #pragma unroll
                    for (int nt = 0; nt < 8; ++nt) {
                        float v = acc[nt][i];
                        if (PRESCALE) v *= dv;
                        Y[(size_t)row * 128 + nt * 16 + m] = f2bf(v);
                    }
                }
            }
        } else {
            float bv[8];
            #pragma unroll
            for (int nt = 0; nt < 8; ++nt) bv[nt] = bias[nt * 16 + m];
            // write this wave's 16 h rows (bias+relu, bf16) into its OWN A-LDS rows (frag layout)
            #pragma unroll
            for (int i = 0; i < 4; ++i) {
                int r = wr + g * 4 + i;
                #pragma unroll
                for (int nt = 0; nt < 8; ++nt) {
                    float v = fmaxf(acc[nt][i] + bv[nt], 0.f);
                    int col = nt * 16 + m;
                    int u = (col >> 3) ^ (r & 7);
                    *(ushort*)(Al + r * 256 + u * 16 + (col & 7) * 2) = f2bf(v);
                }
            }
            __syncthreads();
            float b2v = b2pad[m];
            f32x4 lg = (f32x4){b2v, b2v, b2v, b2v};
            #pragma unroll
            for (int kk = 0; kk < 4; ++kk) {
                int u = (kk * 4 + g) ^ (m & 7);
                s16x8 a = *(const s16x8*)(Al + (wr + m) * 256 + u * 16);
                s16x8 b = *(const s16x8*)(&W2bf[m * 128 + (kk * 4 + g) * 8]);
                lg = __builtin_amdgcn_mfma_f32_16x16x32_bf16(a, b, lg, 0, 0, 0);
            }
            #pragma unroll
            for (int i = 0; i < 4; ++i) {
                float v = lg[i];
                float mx = v;
                #pragma unroll
                for (int off = 8; off > 0; off >>= 1) mx = fmaxf(mx, __shfl_xor(mx, off, 64));
                float ex = expf(v - mx);
                float sm = ex;
                #pragma unroll
                for (int off = 8; off > 0; off >>= 1) sm += __shfl_xor(sm, off, 64);
                float res = v - (mx + logf(sm));
                int grow = rbase + wr + g * 4 + i;
                if (m < 10 && grow < N) OUT[(size_t)grow * 10 + m] = res;
            }
        }
    }
}

// ---------------- Static gather (R11-proven) + self-loop + bias + ReLU + BN stats ----------------
// NO device fences (R10: per-block __threadfence -> 7x). NO work-steal counter (R12: contended
// cross-XCD atomic in chunk-acquisition path -> 5x). Static chunk = blockIdx*4+g.

__global__ __launch_bounds__(256) void gather_fused(const ushort* __restrict__ H,
                                                    const int* __restrict__ row_start,
                                                    const int* __restrict__ csr_src,
                                                    const float* __restrict__ dinv,
                                                    const float* __restrict__ bias,
                                                    ushort* __restrict__ Y,
                                                    float* __restrict__ bnpart, int N) {
    int g = threadIdx.x >> 6, lane = threadIdx.x & 63;
    int d = lane * 2;
    float b0 = bias[d], b1 = bias[d + 1];
    float s0 = 0.f, s1 = 0.f, ss0 = 0.f, ss1 = 0.f;

    int nchunks = (N + 3) / 4;
    int chunk = blockIdx.x * 4 + g;

    if (chunk < nchunks) {
        int c = chunk * 4;
        int nn = min(4, N - c);

        int rsv = row_start[c + min(lane, nn)];
        int rs0 = __shfl(rsv, 0);
        int rs1 = __shfl(rsv, min(1, nn));
        int rs2 = __shfl(rsv, min(2, nn));
        int rs3 = __shfl(rsv, min(3, nn));
        int rs4 = __shfl(rsv, nn);

        float dvv = dinv[c + min(lane, nn - 1)];
        float dv0 = __shfl(dvv, 0);
        float dv1 = __shfl(dvv, min(1, nn - 1));
        float dv2 = __shfl(dvv, min(2, nn - 1));
        float dv3 = __shfl(dvv, min(3, nn - 1));

        uint h0 = *(const uint*)&H[(size_t)c * 128 + d];
        uint h1 = (nn > 1) ? *(const uint*)&H[(size_t)(c + 1) * 128 + d] : 0u;
        uint h2 = (nn > 2) ? *(const uint*)&H[(size_t)(c + 2) * 128 + d] : 0u;
        uint h3 = (nn > 3) ? *(const uint*)&H[(size_t)(c + 3) * 128 + d] : 0u;

        float i0_0 = bflo(h0) * dv0 + b0, i1_0 = bfhi(h0) * dv0 + b1;
        float i0_1 = bflo(h1) * dv1 + b0, i1_1 = bfhi(h1) * dv1 + b1;
        float i0_2 = bflo(h2) * dv2 + b0, i1_2 = bfhi(h2) * dv2 + b1;
        float i0_3 = bflo(h3) * dv3 + b0, i1_3 = bfhi(h3) * dv3 + b1;

        int e0 = rs0, eend = rs4;
        int seg = 0;
        int nextb = rs1;
        float i0s = i0_0, i1s = i1_0, dvs = dv0;
        float es0 = 0.f, es1 = 0.f;

        for (int base = e0; base < eend; base += 64) {
            int cnt = min(64, eend - base);
            int sl = (lane < cnt) ? csr_src[base + lane] : 0;

            for (int j = 0; j < cnt; j += 16) {
                int mm = min(16, cnt - j);
                uint v[16];
                #pragma unroll
                for (int k = 0; k < 16; ++k) {
                    int idx = min(j + k, cnt - 1);
                    int sk = __shfl(sl, idx);
                    v[k] = *(const uint*)&H[(size_t)sk * 128 + d];
                }
                #pragma unroll
                for (int k = 0; k < 16; ++k) {
                    if (k < mm) {
                        int e = base + j + k;
                        while (e >= nextb) {     // uniform boundary crossing
                            float r0 = fmaxf(es0 * dvs + i0s, 0.f);
                            float r1 = fmaxf(es1 * dvs + i1s, 0.f);
                            *(uint*)&Y[(size_t)(c + seg) * 128 + d] =
                                (uint)f2bf(r0) | ((uint)f2bf(r1) << 16);
                            s0 += r0; ss0 += r0 * r0; s1 += r1; ss1 += r1 * r1;
                            seg++;
                            i0s = sel4f(i0_0, i0_1, i0_2, i0_3, seg);
                            i1s = sel4f(i1_0, i1_1, i1_2, i1_3, seg);
                            dvs = sel4f(dv0, dv1, dv2, dv3, seg);
                            nextb = sel4i(rs1, rs2, rs3, rs4, seg);
                            es0 = 0.f; es1 = 0.f;
                        }
                        es0 += bflo(v[k]);
                        es1 += bfhi(v[k]);
                    }
                }
            }
        }
        for (;;) {
            float r0 = fmaxf(es0 * dvs + i0s, 0.f);
            float r1 = fmaxf(es1 * dvs + i1s, 0.f);
            *(uint*)&Y[(size_t)(c + seg) * 128 + d] = (uint)f2bf(r0) | ((uint)f2bf(r1) << 16);
            s0 += r0; ss0 += r0 * r0; s1 += r1; ss1 += r1 * r1;
            seg++;
            if (seg >= nn) break;
            i0s = sel4f(i0_0, i0_1, i0_2, i0_3, seg);
            i1s = sel4f(i1_0, i1_1, i1_2, i1_3, seg);
            dvs = sel4f(dv0, dv1, dv2, dv3, seg);
            nextb = sel4i(rs1, rs2, rs3, rs4, seg);
            es0 = 0.f; es1 = 0.f;
        }
    }

    float* bp = bnpart + (size_t)(blockIdx.x & (NSLOT - 1)) * 256;   // [0..127]=sum [128..255]=ss
    __shared__ float red[4][128];
    red[g][d] = s0; red[g][d + 1] = s1;
    __syncthreads();
    if (g == 0) {
        atomicAdd(&bp[d],     red[0][d] + red[1][d] + red[2][d] + red[3][d]);
        atomicAdd(&bp[d + 1], red[0][d + 1] + red[1][d + 1] + red[2][d + 1] + red[3][d + 1]);
    }
    __syncthreads();
    red[g][d] = ss0; red[g][d + 1] = ss1;
    __syncthreads();
    if (g == 0) {
        atomicAdd(&bp[128 + d],     red[0][d] + red[1][d] + red[2][d] + red[3][d]);
        atomicAdd(&bp[128 + d + 1], red[0][d + 1] + red[1][d + 1] + red[2][d + 1] + red[3][d + 1]);
    }
}

// ---------------- Launch ----------------

static inline char* align16(char* p) { return (char*)(((uintptr_t)p + 15) & ~(uintptr_t)15); }

extern "C" void kernel_launch(void* const* d_in, const int* in_sizes, int n_in,
                              void* d_out, int out_size, void* d_ws, size_t ws_size,
                              hipStream_t stream) {
    const float* x    = (const float*)d_in[0];
    const int*   ei   = (const int*)d_in[1];
    const float* W1   = (const float*)d_in[2];
    const float* b1   = (const float*)d_in[3];
    const float* g1   = (const float*)d_in[4];
    const float* be1  = (const float*)d_in[5];
    const float* W2   = (const float*)d_in[6];
    const float* b2   = (const float*)d_in[7];
    const float* g2   = (const float*)d_in[8];
    const float* be2  = (const float*)d_in[9];
    const float* l1w  = (const float*)d_in[10];
    const float* l1b  = (const float*)d_in[11];
    const float* l2w  = (const float*)d_in[12];
    const float* l2b  = (const float*)d_in[13];
    float* out = (float*)d_out;

    int N = in_sizes[0] / 128;   // 50000
    int E = in_sizes[1] / 2;     // 640000
    const int* srcp = ei;
    const int* dstp = ei + E;

    char* w = (char*)d_ws;
    ushort* bufA   = (ushort*)w;  w = align16(w + (size_t)N * 128 * 2);
    ushort* bufB   = (ushort*)w;  w = align16(w + (size_t)N * 128 * 2);
    // zero region: degc | bnpartA | bnpartB | ctrs (contiguous, uint4-granular)
    char* zstart   = w;
    int*   degc    = (int*)w;     w += (size_t)N * 4;
    float* bnpA    = (float*)w;   w += (size_t)NSLOT * 256 * 4;
    float* bnpB    = (float*)w;   w += (size_t)NSLOT * 256 * 4;
    int*   ctrs    = (int*)w;     w += 16;                     // [0]=scan sync
    size_t zbytes  = (size_t)(w - zstart);
    w = align16(w);
    float* dinv    = (float*)w;   w = align16(w + (size_t)N * 4);
    int*   row_st  = (int*)w;     w = align16(w + (size_t)(N + 1) * 4);
    int*   cursor  = (int*)w;     w = align16(w + (size_t)N * 4);
    int*   bsum    = (int*)w;     w = align16(w + 256 * 4);
    int*   csr_src = (int*)w;     w = align16(w + (size_t)E * 4);
    ushort* wt1    = (ushort*)w;  w = align16(w + 16384 * 2);
    ushort* wt2    = (ushort*)w;  w = align16(w + 16384 * 2);
    ushort* wt3    = (ushort*)w;  w = align16(w + 16384 * 2);
    ushort* w2bf   = (ushort*)w;  w = align16(w + 2048 * 2);
    float* b2pad   = (float*)w;   w = align16(w + 16 * 4);

    int nz = (int)(zbytes / 16);             // uint4 count (zbytes is 16B-multiple)
    int ZB = (nz + 255) / 256;               // zeroing blocks
    int eg4 = (E + 1023) / 1024;
    int ng = (N + 255) / 256;                // scan block count (196 <= 256 CUs)
    int gemm_grid = (N + 127) / 128;         // 391
    int nchunks = (N + 3) / 4;
    int gather_grid = (nchunks + 3) / 4;     // one chunk per wave, 4 waves/block (R11-proven)
    float invN = 1.0f / (float)N;

    // ---- init (zero ∥ weight prep), CSR build ----
    init_prep<<<ZB + 192, 256, 0, stream>>>((uint4*)zstart, nz, ZB,
                                            W1, W2, l1w, l2w, l2b, wt1, wt2, wt3, w2bf, b2pad);
    deg_count<<<eg4, 256, 0, stream>>>(dstp, degc, E);
    scan_fill<<<ng, 256, 0, stream>>>(degc, bsum, &ctrs[0], row_st, cursor, dinv, N, E, ng);
    csr_fill<<<eg4, 256, 0, stream>>>(srcp, dstp, cursor, csr_src, E);

    // ---- layer 1 ----
    gemm_mfma<true, false, true, false><<<gemm_grid, 256, 0, stream>>>(
        x, nullptr, nullptr, nullptr, 0.f, wt1, nullptr, dinv, bufA, nullptr, nullptr, nullptr, N);
    gather_fused<<<gather_grid, 256, 0, stream>>>(bufA, row_st, csr_src, dinv, b1, bufB, bnpA, N);

    // ---- layer 2 (BN1 folded into GEMM prologue from bnpA) ----
    gemm_mfma<false, true, true, false><<<gemm_grid, 256, 0, stream>>>(
        bufB, bnpA, g1, be1, invN, wt2, nullptr, dinv, bufA, nullptr, nullptr, nullptr, N);
    gather_fused<<<gather_grid, 256, 0, stream>>>(bufA, row_st, csr_src, dinv, b2, bufB, bnpB, N);

    // ---- head: lin1 GEMM (BN2 from bnpB) + MFMA logits + lane-tree log_softmax ----
    gemm_mfma<false, true, false, true><<<gemm_grid, 256, 0, stream>>>(
        bufB, bnpB, g2, be2, invN, wt3, l1b, nullptr, nullptr, w2bf, b2pad, out, N);
}